// Round 8
// baseline (201.572 us; speedup 1.0000x reference)
//
#include <hip/hip_runtime.h>

// B=8, L=512, K=512, D=M=N=P=64, all fp32.
// ws: vkc = 8*512*64 floats (1 MB) | wts = 8*512*512 floats (8 MB)

// ---------------------------------------------------------------------------
// K1 (wave-specialized, ZERO barriers, ZERO LDS):
//   waves 0-3: vkc[b,k,n] = sum_p vk[b,k,p,n]*vexp[b,k,p]  (2 rows/wave)
//   waves 4-7: scores+softmax for 2 l-rows/wave, all in registers -> wts
// The 67 MB vk stream (memory pipe) and the L2-hot score compute (VALU pipe)
// co-schedule on every CU; no intra-block dependency between the halves.
// ---------------------------------------------------------------------------
__global__ __launch_bounds__(512) void pre_kernel(const float* __restrict__ q,
                                                  const float* __restrict__ k,
                                                  const float* __restrict__ vk,
                                                  const float* __restrict__ vexp,
                                                  const float* __restrict__ scale_p,
                                                  float* __restrict__ vkc,
                                                  float* __restrict__ wts) {
    const int t = threadIdx.x;
    const int wv = t >> 6;
    const int lane = t & 63;
    const int blk = blockIdx.x;              // 0..511

    if (wv < 4) {
        // ---- vkc: rows blk*8 + wv*2 + {0,1} (proven 16-float4 pattern) ----
        #pragma unroll
        for (int r = 0; r < 2; ++r) {
            const int row = (blk << 3) + (wv << 1) + r;   // b*512 + kk
            const float ve = vexp[row * 64 + lane];
            const int n0 = (lane & 15) << 2;
            const float* base = vk + (long)row * 4096;
            float ax = 0.f, ay = 0.f, az = 0.f, aw = 0.f;
            #pragma unroll
            for (int it = 0; it < 16; ++it) {
                const int p = (lane >> 4) + (it << 2);
                const float4 v4 = *(const float4*)(base + p * 64 + n0);
                const float w = __shfl(ve, p, 64);
                ax += v4.x * w; ay += v4.y * w; az += v4.z * w; aw += v4.w * w;
            }
            ax += __shfl_down(ax, 32, 64); ax += __shfl_down(ax, 16, 64);
            ay += __shfl_down(ay, 32, 64); ay += __shfl_down(ay, 16, 64);
            az += __shfl_down(az, 32, 64); az += __shfl_down(az, 16, 64);
            aw += __shfl_down(aw, 32, 64); aw += __shfl_down(aw, 16, 64);
            if ((lane & 48) == 0) {
                float4 rr; rr.x = ax; rr.y = ay; rr.z = az; rr.w = aw;
                *(float4*)(vkc + row * 64 + n0) = rr;
            }
        }
    } else {
        // ---- scores + softmax, fully in registers ----
        const int batch = blk >> 6;
        const int l0 = (blk & 63) << 3;
        const int lw = l0 + ((wv - 4) << 1);          // first of 2 l-rows
        const float scale = scale_p[0];
        const float* kb = k + batch * 512 * 64;
        const float* q0 = q + (batch * 512 + lw) * 64;   // wave-uniform -> s_load
        const float* q1 = q0 + 64;

        float a0[8], a1[8];
        // lane owns k-rows {c*64 + lane}; chunk-outer keeps L1 footprint 16 KB
        #pragma unroll
        for (int c = 0; c < 8; ++c) {
            const float4* krow = (const float4*)(kb + ((c << 6) + lane) * 64);
            float s0 = 0.f, s1 = 0.f;
            #pragma unroll
            for (int dc = 0; dc < 16; ++dc) {
                const float4 kv = krow[dc];
                const float4 qa = ((const float4*)q0)[dc];   // scalar pipe
                const float4 qb = ((const float4*)q1)[dc];
                s0 += qa.x * kv.x + qa.y * kv.y + qa.z * kv.z + qa.w * kv.w;
                s1 += qb.x * kv.x + qb.y * kv.y + qb.z * kv.z + qb.w * kv.w;
            }
            a0[c] = scale * s0;
            a1[c] = scale * s1;
        }
        // softmax over 512 (8 regs x 64 lanes) for each of the 2 rows
        {
            float mx = -1e30f;
            #pragma unroll
            for (int c = 0; c < 8; ++c) mx = fmaxf(mx, a0[c]);
            #pragma unroll
            for (int off = 32; off; off >>= 1) mx = fmaxf(mx, __shfl_xor(mx, off, 64));
            float s = 0.f;
            #pragma unroll
            for (int c = 0; c < 8; ++c) { a0[c] = __expf(a0[c] - mx); s += a0[c]; }
            #pragma unroll
            for (int off = 32; off; off >>= 1) s += __shfl_xor(s, off, 64);
            const float inv = 1.0f / s;
            float* wrow = wts + (long)(batch * 512 + lw) * 512;
            #pragma unroll
            for (int c = 0; c < 8; ++c) wrow[(c << 6) + lane] = a0[c] * inv;
        }
        {
            float mx = -1e30f;
            #pragma unroll
            for (int c = 0; c < 8; ++c) mx = fmaxf(mx, a1[c]);
            #pragma unroll
            for (int off = 32; off; off >>= 1) mx = fmaxf(mx, __shfl_xor(mx, off, 64));
            float s = 0.f;
            #pragma unroll
            for (int c = 0; c < 8; ++c) { a1[c] = __expf(a1[c] - mx); s += a1[c]; }
            #pragma unroll
            for (int off = 32; off; off >>= 1) s += __shfl_xor(s, off, 64);
            const float inv = 1.0f / s;
            float* wrow = wts + (long)(batch * 512 + lw + 1) * 512;
            #pragma unroll
            for (int c = 0; c < 8; ++c) wrow[(c << 6) + lane] = a1[c] * inv;
        }
    }
}

// ---------------------------------------------------------------------------
// K2: per (batch, 8 l-rows), 512 threads: stage weights -> tmp = w @ vkc
// (proven float4 phase) -> tmp_g.
// ---------------------------------------------------------------------------
__global__ __launch_bounds__(512) void tmp_kernel(const float* __restrict__ vkc,
                                                  const float* __restrict__ wts,
                                                  float* __restrict__ tmp_g) {
    __shared__ float sc[8][512];          // 16 KB (rows contiguous = wts layout)
    __shared__ float tp[8][8][64];        // 16 KB

    const int t = threadIdx.x;
    const int wv = t >> 6;
    const int lane = t & 63;
    const int batch = blockIdx.x >> 6;
    const int l0 = (blockIdx.x & 63) << 3;

    // ---- stage 8 weight rows (4096 floats, 2 float4/thread, coalesced) ----
    {
        const float4* wg = (const float4*)(wts + (long)(batch * 512 + l0) * 512);
        float4* scf = (float4*)sc;
        scf[t] = wg[t];
        scf[t + 512] = wg[t + 512];
    }
    __syncthreads();

    // ---- tmp[l][n] = sum_k w[l][k]*vkc[b][k][n]; wave covers 64 k ----
    {
        const float* vkcb = vkc + batch * 512 * 64;
        const int ksub = lane >> 4;
        const int n0 = (lane & 15) << 2;
        const int kbeg = wv << 6;
        float4 a[8];
        #pragma unroll
        for (int l = 0; l < 8; ++l) { a[l].x = 0.f; a[l].y = 0.f; a[l].z = 0.f; a[l].w = 0.f; }
        #pragma unroll
        for (int i = 0; i < 16; ++i) {
            const int kk = kbeg + (i << 2) + ksub;
            const float4 v4 = *(const float4*)(vkcb + kk * 64 + n0);  // 1 KB/instr
            #pragma unroll
            for (int l = 0; l < 8; ++l) {
                const float w = sc[l][kk];
                a[l].x += w * v4.x; a[l].y += w * v4.y;
                a[l].z += w * v4.z; a[l].w += w * v4.w;
            }
        }
        #pragma unroll
        for (int l = 0; l < 8; ++l) {
            a[l].x += __shfl_down(a[l].x, 32, 64); a[l].x += __shfl_down(a[l].x, 16, 64);
            a[l].y += __shfl_down(a[l].y, 32, 64); a[l].y += __shfl_down(a[l].y, 16, 64);
            a[l].z += __shfl_down(a[l].z, 32, 64); a[l].z += __shfl_down(a[l].z, 16, 64);
            a[l].w += __shfl_down(a[l].w, 32, 64); a[l].w += __shfl_down(a[l].w, 16, 64);
        }
        if (lane < 16) {
            #pragma unroll
            for (int l = 0; l < 8; ++l)
                *(float4*)&tp[wv][l][lane << 2] = a[l];
        }
    }
    __syncthreads();
    {   // reduce the 8 wave partials and write tmp to global (coalesced)
        float s = tp[0][wv][lane];
        #pragma unroll
        for (int w = 1; w < 8; ++w) s += tp[w][wv][lane];
        tmp_g[(batch * 512 + l0) * 64 + t] = s;
    }
}

// ---------------------------------------------------------------------------
// K3 (proven): one wave per (b,l) row: attn = vq.tmp -> residual + LN.
// Zero block barriers; 16 hoisted 1 KB coalesced loads per wave.
// ---------------------------------------------------------------------------
__global__ __launch_bounds__(256) void out_kernel(const float* __restrict__ q,
                                                  const float* __restrict__ vq,
                                                  const float* __restrict__ tmp_g,
                                                  const float* __restrict__ gamma,
                                                  const float* __restrict__ beta,
                                                  float* __restrict__ out) {
    __shared__ float attn_s[4][64];

    const int wv = threadIdx.x >> 6;
    const int lane = threadIdx.x & 63;
    const int row = (blockIdx.x << 2) + wv;        // b*512 + l

    const float* vql = vq + (long)row * 4096;

    float4 v[16];
    #pragma unroll
    for (int it = 0; it < 16; ++it)
        v[it] = *(const float4*)(vql + it * 256 + lane * 4);

    const float qv = q[row * 64 + lane];
    const int n0 = (lane & 15) << 2;
    const float4 t4 = *(const float4*)(tmp_g + row * 64 + n0);

    #pragma unroll
    for (int it = 0; it < 16; ++it) {
        float part = v[it].x * t4.x + v[it].y * t4.y + v[it].z * t4.z + v[it].w * t4.w;
        part += __shfl_down(part, 8, 16);
        part += __shfl_down(part, 4, 16);
        part += __shfl_down(part, 2, 16);
        part += __shfl_down(part, 1, 16);
        if ((lane & 15) == 0) attn_s[wv][it * 4 + (lane >> 4)] = part;
    }
    // attn_s[wv] produced+consumed by the same wave -> no block barrier

    const float x = qv + attn_s[wv][lane];
    float s1 = x, s2 = x * x;
    #pragma unroll
    for (int off = 32; off; off >>= 1) {
        s1 += __shfl_xor(s1, off, 64);
        s2 += __shfl_xor(s2, off, 64);
    }
    const float mean = s1 * (1.0f / 64.0f);
    const float var = s2 * (1.0f / 64.0f) - mean * mean;
    const float r = rsqrtf(var + 1e-3f);
    out[row * 64 + lane] = (x - mean) * r * gamma[lane] + beta[lane];
}

extern "C" void kernel_launch(void* const* d_in, const int* in_sizes, int n_in,
                              void* d_out, int out_size, void* d_ws, size_t ws_size,
                              hipStream_t stream) {
    const float* q     = (const float*)d_in[0];
    const float* k     = (const float*)d_in[1];
    const float* vq    = (const float*)d_in[2];
    const float* vk    = (const float*)d_in[3];
    const float* vexp  = (const float*)d_in[4];
    const float* scale = (const float*)d_in[5];
    const float* gamma = (const float*)d_in[6];
    const float* beta  = (const float*)d_in[7];
    float* out = (float*)d_out;

    float* vkc = (float*)d_ws;                 // 1 MB
    float* wts = vkc + 8 * 512 * 64;           // 8 MB
    float* tmp = wts + 8 * 512 * 512;          // 1 MB

    pre_kernel<<<512, 512, 0, stream>>>(q, k, vk, vexp, scale, vkc, wts);
    tmp_kernel<<<512, 512, 0, stream>>>(vkc, wts, tmp);
    out_kernel<<<1024, 256, 0, stream>>>(q, vq, tmp, gamma, beta, out);
}